// Round 7
// baseline (603.944 us; speedup 1.0000x reference)
//
#include <hip/hip_runtime.h>
#include <hip/hip_bf16.h>

typedef unsigned short ushort_t;
typedef __attribute__((ext_vector_type(4))) float f32x4;
typedef __attribute__((ext_vector_type(8))) short bf16x8;
typedef __attribute__((ext_vector_type(8))) unsigned short us8;

#define T_TOK 4096
#define D_DIM 1024
#define FF_DIM 4096
#define NE 8
#define ESTRIDE 4194304L  // 4096*1024 elements per expert weight matrix

__device__ __forceinline__ unsigned short f2bf(float f) {
  __hip_bfloat16 h = __float2bfloat16(f);
  return __builtin_bit_cast(unsigned short, h);
}
__device__ __forceinline__ float gelu_f(float v) {
  return 0.5f * v * (1.0f + erff(v * 0.70710678118654752440f));
}

// ---------------- gating: logits -> softmax top2 -> expert lists -------------
__global__ void gate_kernel(const float* __restrict__ x, const float* __restrict__ Wg,
                            int* __restrict__ cnt, int* __restrict__ tok,
                            float* __restrict__ wof, int* __restrict__ rankof) {
  const int t = blockIdx.x;
  const int lane = threadIdx.x;  // 64 threads = 1 wave
  const float* xr = x + (long)t * D_DIM;
  float acc[NE];
#pragma unroll
  for (int e = 0; e < NE; e++) acc[e] = 0.f;
#pragma unroll
  for (int i = 0; i < 16; i++) {
    int d = i * 64 + lane;
    float xv = xr[d];
    const float* wr = Wg + d * NE;
#pragma unroll
    for (int e = 0; e < NE; e++) acc[e] += xv * wr[e];
  }
#pragma unroll
  for (int off = 32; off > 0; off >>= 1) {
#pragma unroll
    for (int e = 0; e < NE; e++) acc[e] += __shfl_xor(acc[e], off, 64);
  }
  if (lane == 0) {
    int i0 = 0;
#pragma unroll
    for (int e = 1; e < NE; e++) if (acc[e] > acc[i0]) i0 = e;
    int i1 = -1;
#pragma unroll
    for (int e = 0; e < NE; e++) {
      if (e == i0) continue;
      if (i1 < 0 || acc[e] > acc[i1]) i1 = e;
    }
    float e1 = expf(acc[i1] - acc[i0]);
    float w0 = 1.f / (1.f + e1);
    float w1 = e1 * w0;
    int s0 = atomicAdd(&cnt[i0], 1);
    tok[i0 * T_TOK + s0] = t; wof[i0 * T_TOK + s0] = w0; rankof[i0 * T_TOK + s0] = 0;
    int s1 = atomicAdd(&cnt[i1], 1);
    tok[i1 * T_TOK + s1] = t; wof[i1 * T_TOK + s1] = w1; rankof[i1 * T_TOK + s1] = 1;
    tok[8 * T_TOK + t] = t; wof[8 * T_TOK + t] = 1.f; rankof[8 * T_TOK + t] = 0;
  }
}

__global__ void scan_kernel(int* cnt, int* base) {
  if (threadIdx.x == 0 && blockIdx.x == 0) {
    int s = 0;
    for (int e = 0; e < NE; e++) { base[e] = s; s += cnt[e]; }
    base[8] = s;      // always 8192
    cnt[8] = T_TOK;   // shared pseudo-expert gets all tokens
  }
}

// ---------------- build work-item queues (no dead blocks) -------------------
// m-tile = 128 rows. Ordered (e, nx, my): consecutive items share the B
// weight panel (the HBM-heavy stream) for L2 reuse. nq[0]=|q1|, nq[1]=|q2|.
__global__ void build_queue_kernel(const int* __restrict__ cnt,
                                   unsigned int* __restrict__ q1,
                                   unsigned int* __restrict__ q2,
                                   int* __restrict__ nq) {
  const int e = blockIdx.x;  // 9 blocks
  int off1 = 0, off2 = 0, tot1 = 0, tot2 = 0, mym = 0;
  for (int i = 0; i < 9; i++) {
    int c = (i == 8) ? T_TOK : cnt[i];
    int m = (c + 127) >> 7;
    if (i < e) { off1 += m * 32; off2 += m * 8; }
    if (i == e) mym = m;
    tot1 += m * 32; tot2 += m * 8;
  }
  for (int nx = 0; nx < 32; nx++)
    for (int my = threadIdx.x; my < mym; my += 256)
      q1[off1 + nx * mym + my] = ((unsigned)e << 16) | ((unsigned)my << 8) | (unsigned)nx;
  for (int nx = 0; nx < 8; nx++)
    for (int my = threadIdx.x; my < mym; my += 256)
      q2[off2 + nx * mym + my] = ((unsigned)e << 16) | ((unsigned)my << 8) | (unsigned)nx;
  if (e == 0 && threadIdx.x == 0) { nq[0] = tot1; nq[1] = tot2; }
}

// ---------------- fp32 -> bf16 convert (x) ----------------------------------
__global__ void cvt_x_kernel(const float* __restrict__ src, ushort_t* __restrict__ dst) {
  long i = ((long)blockIdx.x * 256 + threadIdx.x) * 8;
  float4 v0 = *(const float4*)(src + i);
  float4 v1 = *(const float4*)(src + i + 4);
  us8 o;
  o[0] = f2bf(v0.x); o[1] = f2bf(v0.y); o[2] = f2bf(v0.z); o[3] = f2bf(v0.w);
  o[4] = f2bf(v1.x); o[5] = f2bf(v1.y); o[6] = f2bf(v1.z); o[7] = f2bf(v1.w);
  *(us8*)(dst + i) = o;
}

// ---------------- fp32 [R][C] -> bf16 [C][R] transpose-convert --------------
__global__ void tcvt_kernel(const float* __restrict__ src, ushort_t* __restrict__ dst,
                            int R, int C) {
  src += (long)blockIdx.z * R * C;
  dst += (long)blockIdx.z * R * C;
  const int r0 = blockIdx.y * 64, c0 = blockIdx.x * 64;
  __shared__ ushort_t tile[64][72];
  const int t = threadIdx.x;
#pragma unroll
  for (int i = 0; i < 4; i++) {
    int lin = t + i * 256;
    int r = lin >> 4;
    int c = (lin & 15) * 4;
    float4 v = *(const float4*)(src + (long)(r0 + r) * C + c0 + c);
    tile[c + 0][r] = f2bf(v.x);
    tile[c + 1][r] = f2bf(v.y);
    tile[c + 2][r] = f2bf(v.z);
    tile[c + 3][r] = f2bf(v.w);
  }
  __syncthreads();
#pragma unroll
  for (int i = 0; i < 2; i++) {
    int lin = t + i * 256;
    int cc = lin >> 3, rp = lin & 7;
    us8 v = *(const us8*)&tile[cc][rp * 8];
    *(us8*)(dst + (long)(c0 + cc) * R + r0 + rp * 8) = v;
  }
}

// ---------------- GEMM: m97 structure, BK=64, 128x128 tile, 4 waves ---------
// Single 32 KiB LDS buffer, 2 barriers per K-64 step (half the latency events
// of BK=32). XOR swizzle for the 128-B rows (G4 case): stored 16B-slot =
// global_chunk ^ (row&7); inverse applied on per-lane GLOBAL source, LDS dest
// linear (rule #21). kk=1 sub-tile read = offset ^ 64 (slot bit2 <-> byte
// bit6). __launch_bounds__(256,3): regs <=170 (no spill), 3 blocks/CU target.
// Queue-driven; grid ~= item count (no dead-block dilution).
// PHASE 1: He = gelu(gather(Xbf) @ W1T^T + b1)   (K=1024, N=4096)
// PHASE 2: ybuf/out = route(He @ W2T^T + b2)     (K=4096, N=1024)
template <int K, int N, int PHASE>
__global__ __launch_bounds__(256, 3) void gemm_kernel(
    const ushort_t* __restrict__ Abase, const ushort_t* __restrict__ WT,
    const float* __restrict__ bias_e, const float* __restrict__ bias_s,
    const int* __restrict__ cnt, const int* __restrict__ base,
    const int* __restrict__ tok, const float* __restrict__ wof,
    const int* __restrict__ rankof,
    const unsigned int* __restrict__ q, const int* __restrict__ nq_all,
    ushort_t* __restrict__ He, float* __restrict__ ybuf, float* __restrict__ out) {
  const int nq = nq_all[PHASE - 1];
  const int tid = threadIdx.x;
  const int w = tid >> 6, lane = tid & 63;
  const int wm = w >> 1, wn = w & 1;
  const int lr = lane & 15, lg = lane >> 4;

  __shared__ ushort_t lds_u[2 * 8192];  // A 16 KiB @0, B 16 KiB @16384
  char* const lds = (char*)lds_u;

  // staging: chunk id c = i*256 + tid -> LDS byte c*16 (lane-contiguous per
  // wave: c = (i*256 + w*64) + lane). row = c>>3 = i*32 + (tid>>3),
  // stored slot = tid&7, global chunk g = (tid&7) ^ (row&7).
  const int srow8 = tid >> 3;                    // 0..31
  const int g8 = (tid & 7) ^ (srow8 & 7);        // inverse-swizzled k-chunk

  // read offsets (kk=0); kk=1 = ^64
  int offA[4], offB[4];
#pragma unroll
  for (int m = 0; m < 4; m++) {
    int r = wm * 64 + m * 16 + lr;
    offA[m] = r * 128 + ((lg ^ (r & 7)) << 4);
  }
#pragma unroll
  for (int n = 0; n < 4; n++) {
    int r = wn * 64 + n * 16 + lr;
    offB[n] = r * 128 + ((lg ^ (r & 7)) << 4);
  }

  for (int it = blockIdx.x; it < nq; it += gridDim.x) {
    const unsigned int item = q[it];
    const int e = item >> 16;
    const int m0 = ((item >> 8) & 0xff) * 128;
    const int n0 = (item & 0xff) * 128;
    const int count = cnt[e];

    const ushort_t* pA[4];
    const ushort_t* pB[4];
#pragma unroll
    for (int i = 0; i < 4; i++) {
      int rr = m0 + i * 32 + srow8;
      int rc = (rr < count) ? rr : 0;  // clamp OOB rows
      long arow;
      if (PHASE == 1) arow = tok[e * T_TOK + rc];
      else            arow = (long)base[e] + rc;
      pA[i] = Abase + arow * (long)K + g8 * 8;
      pB[i] = WT + (long)e * ESTRIDE + (long)(n0 + i * 32 + srow8) * K + g8 * 8;
    }

    f32x4 acc[4][4] = {};

    for (int k0 = 0; k0 < K; k0 += 64) {
#pragma unroll
      for (int i = 0; i < 4; i++) {
        __builtin_amdgcn_global_load_lds(
            (const __attribute__((address_space(1))) void*)(pA[i] + k0),
            (__attribute__((address_space(3))) void*)(lds + i * 4096 + tid * 16), 16, 0, 0);
        __builtin_amdgcn_global_load_lds(
            (const __attribute__((address_space(1))) void*)(pB[i] + k0),
            (__attribute__((address_space(3))) void*)(lds + 16384 + i * 4096 + tid * 16),
            16, 0, 0);
      }
      __syncthreads();  // drain vmcnt(0): tile resident; barrier

#pragma unroll
      for (int kk = 0; kk < 2; kk++) {
        const int kx = kk << 6;
        bf16x8 av[4], bv[4];
#pragma unroll
        for (int m = 0; m < 4; m++)
          av[m] = *(const bf16x8*)(lds + (offA[m] ^ kx));
#pragma unroll
        for (int n = 0; n < 4; n++)
          bv[n] = *(const bf16x8*)(lds + 16384 + (offB[n] ^ kx));
#pragma unroll
        for (int m = 0; m < 4; m++)
#pragma unroll
          for (int n = 0; n < 4; n++)
            acc[m][n] = __builtin_amdgcn_mfma_f32_16x16x32_bf16(av[m], bv[n], acc[m][n], 0, 0, 0);
      }
      __syncthreads();  // all reads done before next stage overwrites
    }

    const float* bias = (e == NE) ? bias_s : (bias_e + (long)e * N);
#pragma unroll
    for (int m = 0; m < 4; m++) {
#pragma unroll
      for (int j = 0; j < 4; j++) {
        int rloc = wm * 64 + m * 16 + lg * 4 + j;  // D row = (lane>>4)*4 + reg
        int rr = m0 + rloc;
        if (rr >= count) continue;
        if (PHASE == 1) {
          long orow = (long)base[e] + rr;
#pragma unroll
          for (int n = 0; n < 4; n++) {
            int col = n0 + wn * 64 + n * 16 + lr;  // D col = lane&15
            float v = acc[m][n][j] + bias[col];
            He[orow * FF_DIM + col] = f2bf(gelu_f(v));
          }
        } else {
          int tt = tok[e * T_TOK + rr];
          if (e == NE) {  // shared FFN -> d_out directly
#pragma unroll
            for (int n = 0; n < 4; n++) {
              int col = n0 + wn * 64 + n * 16 + lr;
              out[(long)tt * D_DIM + col] = acc[m][n][j] + bias[col];
            }
          } else {
            float wgt = wof[e * T_TOK + rr];
            int rk = rankof[e * T_TOK + rr];
            float* dst = ybuf + (long)rk * ((long)T_TOK * D_DIM) + (long)tt * D_DIM;
#pragma unroll
            for (int n = 0; n < 4; n++) {
              int col = n0 + wn * 64 + n * 16 + lr;
              dst[col] = wgt * (acc[m][n][j] + bias[col]);
            }
          }
        }
      }
    }
    // K-loop ended with __syncthreads(); epilogue touches no LDS -> next
    // item's stage is safe.
  }
}

// ---------------- final: out += y_rank0 + y_rank1 ---------------------------
__global__ void final_add_kernel(float* __restrict__ out, const float* __restrict__ ybuf) {
  long i = ((long)blockIdx.x * 256 + threadIdx.x) * 4;
  float4 a = *(const float4*)(out + i);
  float4 b = *(const float4*)(ybuf + i);
  float4 c = *(const float4*)(ybuf + (long)T_TOK * D_DIM + i);
  a.x += b.x + c.x; a.y += b.y + c.y; a.z += b.z + c.z; a.w += b.w + c.w;
  *(float4*)(out + i) = a;
}

extern "C" void kernel_launch(void* const* d_in, const int* in_sizes, int n_in,
                              void* d_out, int out_size, void* d_ws, size_t ws_size,
                              hipStream_t stream) {
  (void)in_sizes; (void)n_in; (void)out_size; (void)ws_size;
  const float* x   = (const float*)d_in[0];
  const float* Wg  = (const float*)d_in[1];
  const float* W1  = (const float*)d_in[2];
  const float* b1  = (const float*)d_in[3];
  const float* W2  = (const float*)d_in[4];
  const float* b2  = (const float*)d_in[5];
  const float* Ws1 = (const float*)d_in[6];
  const float* bs1 = (const float*)d_in[7];
  const float* Ws2 = (const float*)d_in[8];
  const float* bs2 = (const float*)d_in[9];
  float* out = (float*)d_out;

  char* ws = (char*)d_ws;
  int*      cnt    = (int*)(ws + 0);
  int*      base   = (int*)(ws + 64);
  int*      tok    = (int*)(ws + 256);
  float*    wof    = (float*)(ws + 256 + 147456);
  int*      rankof = (int*)(ws + 256 + 2 * 147456);
  ushort_t* Xbf    = (ushort_t*)(ws + 442624);
  ushort_t* W1T    = (ushort_t*)(ws + 8831232);
  ushort_t* W2T    = (ushort_t*)(ws + 84328704);
  ushort_t* He     = (ushort_t*)(ws + 159826176);     // 12288 x 4096 bf16
  int*      nq     = (int*)(ws + 260489472);
  unsigned int* q1 = (unsigned int*)(ws + 260489536);          // <= 14 KB used
  unsigned int* q2 = (unsigned int*)(ws + 260489536 + 32768);  // <= 4 KB used
  float*    ybuf   = (float*)(ws + 261538048);

  hipMemsetAsync(cnt, 0, 64, stream);
  gate_kernel<<<T_TOK, 64, 0, stream>>>(x, Wg, cnt, tok, wof, rankof);
  scan_kernel<<<1, 64, 0, stream>>>(cnt, base);
  build_queue_kernel<<<9, 256, 0, stream>>>(cnt, q1, q2, nq);
  cvt_x_kernel<<<2048, 256, 0, stream>>>(x, Xbf);
  tcvt_kernel<<<dim3(64, 16, 8), 256, 0, stream>>>(W1, W1T, 1024, 4096);
  tcvt_kernel<<<dim3(16, 64, 8), 256, 0, stream>>>(W2, W2T, 4096, 1024);
  tcvt_kernel<<<dim3(64, 16, 1), 256, 0, stream>>>(Ws1, W1T + 8L * ESTRIDE, 1024, 4096);
  tcvt_kernel<<<dim3(16, 64, 1), 256, 0, stream>>>(Ws2, W2T + 8L * ESTRIDE, 4096, 1024);
  gemm_kernel<1024, 4096, 1><<<3328, 256, 0, stream>>>(
      Xbf, W1T, b1, bs1, cnt, base, tok, wof, rankof, q1, nq, He, ybuf, out);
  gemm_kernel<4096, 1024, 2><<<832, 256, 0, stream>>>(
      He, W2T, b2, bs2, cnt, base, tok, wof, rankof, q2, nq, He, ybuf, out);
  final_add_kernel<<<4096, 256, 0, stream>>>(out, ybuf);
}

// Round 8
// 547.856 us; speedup vs baseline: 1.1024x; 1.1024x over previous
//
#include <hip/hip_runtime.h>
#include <hip/hip_bf16.h>

typedef unsigned short ushort_t;
typedef __attribute__((ext_vector_type(4))) float f32x4;
typedef __attribute__((ext_vector_type(8))) short bf16x8;
typedef __attribute__((ext_vector_type(8))) unsigned short us8;

#define T_TOK 4096
#define D_DIM 1024
#define FF_DIM 4096
#define NE 8
#define ESTRIDE 4194304L  // 4096*1024 elements per expert weight matrix

__device__ __forceinline__ unsigned short f2bf(float f) {
  __hip_bfloat16 h = __float2bfloat16(f);
  return __builtin_bit_cast(unsigned short, h);
}
__device__ __forceinline__ float gelu_f(float v) {
  return 0.5f * v * (1.0f + erff(v * 0.70710678118654752440f));
}

// ---------------- gating: logits -> softmax top2 -> expert lists -------------
__global__ void gate_kernel(const float* __restrict__ x, const float* __restrict__ Wg,
                            int* __restrict__ cnt, int* __restrict__ tok,
                            float* __restrict__ wof, int* __restrict__ rankof) {
  const int t = blockIdx.x;
  const int lane = threadIdx.x;  // 64 threads = 1 wave
  const float* xr = x + (long)t * D_DIM;
  float acc[NE];
#pragma unroll
  for (int e = 0; e < NE; e++) acc[e] = 0.f;
#pragma unroll
  for (int i = 0; i < 16; i++) {
    int d = i * 64 + lane;
    float xv = xr[d];
    const float* wr = Wg + d * NE;
#pragma unroll
    for (int e = 0; e < NE; e++) acc[e] += xv * wr[e];
  }
#pragma unroll
  for (int off = 32; off > 0; off >>= 1) {
#pragma unroll
    for (int e = 0; e < NE; e++) acc[e] += __shfl_xor(acc[e], off, 64);
  }
  if (lane == 0) {
    int i0 = 0;
#pragma unroll
    for (int e = 1; e < NE; e++) if (acc[e] > acc[i0]) i0 = e;
    int i1 = -1;
#pragma unroll
    for (int e = 0; e < NE; e++) {
      if (e == i0) continue;
      if (i1 < 0 || acc[e] > acc[i1]) i1 = e;
    }
    float e1 = expf(acc[i1] - acc[i0]);
    float w0 = 1.f / (1.f + e1);
    float w1 = e1 * w0;
    int s0 = atomicAdd(&cnt[i0], 1);
    tok[i0 * T_TOK + s0] = t; wof[i0 * T_TOK + s0] = w0; rankof[i0 * T_TOK + s0] = 0;
    int s1 = atomicAdd(&cnt[i1], 1);
    tok[i1 * T_TOK + s1] = t; wof[i1 * T_TOK + s1] = w1; rankof[i1 * T_TOK + s1] = 1;
    tok[8 * T_TOK + t] = t; wof[8 * T_TOK + t] = 1.f; rankof[8 * T_TOK + t] = 0;
  }
}

__global__ void scan_kernel(int* cnt, int* base) {
  if (threadIdx.x == 0 && blockIdx.x == 0) {
    int s = 0;
    for (int e = 0; e < NE; e++) { base[e] = s; s += cnt[e]; }
    base[8] = s;      // always 8192
    cnt[8] = T_TOK;   // shared pseudo-expert gets all tokens
  }
}

// ---------------- build work-item queues, supertile-ordered -----------------
// GEMM1: supertile 4my x 8nx (A 1MB + B 2MB fits 4MB L2); GEMM2: 2my x 2nx.
// Order: (e, msup, nsup, mi, ni) -> consecutive queue items share panels; with
// XCD-chunked block swizzle each XCD's L2 holds one supertile's working set.
__global__ void build_queue_kernel(const int* __restrict__ cnt,
                                   unsigned int* __restrict__ q1,
                                   unsigned int* __restrict__ q2,
                                   int* __restrict__ nq) {
  const int e = blockIdx.x;  // 9 blocks
  int off1 = 0, off2 = 0, tot1 = 0, tot2 = 0, M = 0;
  for (int i = 0; i < 9; i++) {
    int c = (i == 8) ? T_TOK : cnt[i];
    int m = (c + 127) >> 7;
    if (i < e) { off1 += m * 32; off2 += m * 8; }
    if (i == e) M = m;
    tot1 += m * 32; tot2 += m * 8;
  }
  for (int i = threadIdx.x; i < M * 32; i += 256) {
    int my = i >> 5, nx = i & 31;
    int ms = my >> 2, mi = my & 3, ns = nx >> 3, ni = nx & 7;
    int h = M - ms * 4; if (h > 4) h = 4;
    int pos = ms * 128 + ns * (h * 8) + mi * 8 + ni;
    q1[off1 + pos] = ((unsigned)e << 16) | ((unsigned)my << 8) | (unsigned)nx;
  }
  for (int i = threadIdx.x; i < M * 8; i += 256) {
    int my = i >> 3, nx = i & 7;
    int ms = my >> 1, mi = my & 1, ns = nx >> 1, ni = nx & 1;
    int h = M - ms * 2; if (h > 2) h = 2;
    int pos = ms * 16 + ns * (h * 2) + mi * 2 + ni;
    q2[off2 + pos] = ((unsigned)e << 16) | ((unsigned)my << 8) | (unsigned)nx;
  }
  if (e == 0 && threadIdx.x == 0) { nq[0] = tot1; nq[1] = tot2; }
}

// ---------------- fp32 -> bf16 convert (x) ----------------------------------
__global__ void cvt_x_kernel(const float* __restrict__ src, ushort_t* __restrict__ dst) {
  long i = ((long)blockIdx.x * 256 + threadIdx.x) * 8;
  float4 v0 = *(const float4*)(src + i);
  float4 v1 = *(const float4*)(src + i + 4);
  us8 o;
  o[0] = f2bf(v0.x); o[1] = f2bf(v0.y); o[2] = f2bf(v0.z); o[3] = f2bf(v0.w);
  o[4] = f2bf(v1.x); o[5] = f2bf(v1.y); o[6] = f2bf(v1.z); o[7] = f2bf(v1.w);
  *(us8*)(dst + i) = o;
}

// ---------------- fp32 [R][C] -> bf16 [C][R] transpose-convert --------------
// 128-row x 64-col tiles (256B write runs); z=9 merges shared weights (z==8).
__global__ void tcvt_kernel(const float* __restrict__ W, const float* __restrict__ Wsh,
                            ushort_t* __restrict__ dst, int R, int C) {
  const float* src = (blockIdx.z == 8) ? Wsh : (W + (long)blockIdx.z * R * C);
  ushort_t* d = dst + (long)blockIdx.z * R * C;
  const int r0 = blockIdx.y * 128, c0 = blockIdx.x * 64;
  __shared__ ushort_t tile[64][136];  // 272B rows: 16B-aligned
  const int t = threadIdx.x;
#pragma unroll
  for (int i = 0; i < 8; i++) {
    int lin = t + i * 256;
    int r = lin >> 4;
    int c = (lin & 15) * 4;
    float4 v = *(const float4*)(src + (long)(r0 + r) * C + c0 + c);
    tile[c + 0][r] = f2bf(v.x);
    tile[c + 1][r] = f2bf(v.y);
    tile[c + 2][r] = f2bf(v.z);
    tile[c + 3][r] = f2bf(v.w);
  }
  __syncthreads();
#pragma unroll
  for (int i = 0; i < 4; i++) {
    int lin = t + i * 256;
    int cc = lin >> 4, rp = lin & 15;
    us8 v = *(const us8*)&tile[cc][rp * 8];
    *(us8*)(d + (long)(c0 + cc) * R + r0 + rp * 8) = v;
  }
}

// ---------------- GEMM: 128x128 tile, BK=64, counted-vmcnt double buffer ----
// Per K-tile: issue STAGE(t+1) -> s_waitcnt vmcnt(8) (tile t resident, t+1's 8
// loads stay in flight -- NEVER drains to 0 mid-loop) -> barrier -> ds_read +
// 32 MFMA -> barrier (reads done before next STAGE overwrites). 64 KiB LDS ->
// 2 blocks/CU. XOR swizzle (r7-proven, 0 conflicts): stored 16B-slot =
// chunk ^ (row&7), inverse on per-lane GLOBAL source, LDS linear; kk=1 = ^64.
// XCD-chunked swizzle: vbid = (bid&7)*chunk + bid>>3 -> contiguous queue run
// per XCD -> supertile panels L2-resident.
template <int K, int N, int PHASE>
__global__ __launch_bounds__(256, 2) void gemm_kernel(
    const ushort_t* __restrict__ Abase, const ushort_t* __restrict__ WT,
    const float* __restrict__ bias_e, const float* __restrict__ bias_s,
    const int* __restrict__ cnt, const int* __restrict__ base,
    const int* __restrict__ tok, const float* __restrict__ wof,
    const int* __restrict__ rankof,
    const unsigned int* __restrict__ q, const int* __restrict__ nq_all,
    ushort_t* __restrict__ He, float* __restrict__ ybuf, float* __restrict__ out) {
  const int nq = nq_all[PHASE - 1];
  const int tid = threadIdx.x;
  const int w = tid >> 6, lane = tid & 63;
  const int wm = w >> 1, wn = w & 1;
  const int lr = lane & 15, lg = lane >> 4;

  __shared__ ushort_t lds_u[2 * 16384];  // 2 bufs x (A 16KB + B 16KB) = 64 KiB
  char* const lds = (char*)lds_u;

  const int srow8 = tid >> 3;
  const int g8 = (tid & 7) ^ (srow8 & 7);  // inverse-swizzled k-chunk

  int offA[4], offB[4];
#pragma unroll
  for (int m = 0; m < 4; m++) {
    int r = wm * 64 + m * 16 + lr;
    offA[m] = r * 128 + ((lg ^ (r & 7)) << 4);
  }
#pragma unroll
  for (int n = 0; n < 4; n++) {
    int r = wn * 64 + n * 16 + lr;
    offB[n] = r * 128 + ((lg ^ (r & 7)) << 4);
  }

  constexpr int NT = K / 64;
  const int chunk = gridDim.x >> 3;
  const int vbid = (blockIdx.x & 7) * chunk + (blockIdx.x >> 3);

#define STAGE(buf_, kk_)                                                         \
  do {                                                                           \
    char* dd_ = lds + (buf_) * 32768 + tid * 16;                                 \
    _Pragma("unroll")                                                            \
    for (int i_ = 0; i_ < 4; i_++) {                                             \
      __builtin_amdgcn_global_load_lds(                                          \
          (const __attribute__((address_space(1))) void*)(pA[i_] + (kk_)),       \
          (__attribute__((address_space(3))) void*)(dd_ + i_ * 4096), 16, 0, 0); \
      __builtin_amdgcn_global_load_lds(                                          \
          (const __attribute__((address_space(1))) void*)(pB[i_] + (kk_)),       \
          (__attribute__((address_space(3))) void*)(dd_ + 16384 + i_ * 4096),    \
          16, 0, 0);                                                             \
    }                                                                            \
  } while (0)

  for (int it = vbid; it < nq; it += gridDim.x) {
    const unsigned int item = q[it];
    const int e = item >> 16;
    const int m0 = ((item >> 8) & 0xff) * 128;
    const int n0 = (item & 0xff) * 128;
    const int count = cnt[e];

    const ushort_t* pA[4];
    const ushort_t* pB[4];
#pragma unroll
    for (int i = 0; i < 4; i++) {
      int rr = m0 + i * 32 + srow8;
      int rc = (rr < count) ? rr : 0;  // clamp OOB rows
      long arow;
      if (PHASE == 1) arow = tok[e * T_TOK + rc];
      else            arow = (long)base[e] + rc;
      pA[i] = Abase + arow * (long)K + g8 * 8;
      pB[i] = WT + (long)e * ESTRIDE + (long)(n0 + i * 32 + srow8) * K + g8 * 8;
    }

    f32x4 acc[4][4] = {};

    __builtin_amdgcn_s_barrier();            // prev item's last reads done
    asm volatile("" ::: "memory");
    STAGE(0, 0);

    for (int t = 0; t < NT; t++) {
      if (t + 1 < NT) {
        STAGE((t + 1) & 1, (t + 1) * 64);
        asm volatile("s_waitcnt vmcnt(8)" ::: "memory");  // tile t resident
      } else {
        asm volatile("s_waitcnt vmcnt(0)" ::: "memory");
      }
      __builtin_amdgcn_s_barrier();          // all waves confirm tile t
      asm volatile("" ::: "memory");

      const char* aB = lds + (t & 1) * 32768;
      const char* bB = aB + 16384;
#pragma unroll
      for (int kk = 0; kk < 2; kk++) {
        const int kx = kk << 6;
        bf16x8 av[4], bv[4];
#pragma unroll
        for (int m = 0; m < 4; m++)
          av[m] = *(const bf16x8*)(aB + (offA[m] ^ kx));
#pragma unroll
        for (int n = 0; n < 4; n++)
          bv[n] = *(const bf16x8*)(bB + (offB[n] ^ kx));
#pragma unroll
        for (int m = 0; m < 4; m++)
#pragma unroll
          for (int n = 0; n < 4; n++)
            acc[m][n] = __builtin_amdgcn_mfma_f32_16x16x32_bf16(av[m], bv[n], acc[m][n], 0, 0, 0);
      }
      __builtin_amdgcn_s_barrier();          // reads(t) done before overwrite
      asm volatile("" ::: "memory");
    }

    const float* bias = (e == NE) ? bias_s : (bias_e + (long)e * N);
#pragma unroll
    for (int m = 0; m < 4; m++) {
#pragma unroll
      for (int j = 0; j < 4; j++) {
        int rloc = wm * 64 + m * 16 + lg * 4 + j;  // D row = (lane>>4)*4 + reg
        int rr = m0 + rloc;
        if (rr >= count) continue;
        if (PHASE == 1) {
          long orow = (long)base[e] + rr;
#pragma unroll
          for (int n = 0; n < 4; n++) {
            int col = n0 + wn * 64 + n * 16 + lr;  // D col = lane&15
            float v = acc[m][n][j] + bias[col];
            He[orow * FF_DIM + col] = f2bf(gelu_f(v));
          }
        } else {
          int tt = tok[e * T_TOK + rr];
          if (e == NE) {  // shared FFN -> d_out directly
#pragma unroll
            for (int n = 0; n < 4; n++) {
              int col = n0 + wn * 64 + n * 16 + lr;
              out[(long)tt * D_DIM + col] = acc[m][n][j] + bias[col];
            }
          } else {
            float wgt = wof[e * T_TOK + rr];
            int rk = rankof[e * T_TOK + rr];
            float* dst = ybuf + (long)rk * ((long)T_TOK * D_DIM) + (long)tt * D_DIM;
#pragma unroll
            for (int n = 0; n < 4; n++) {
              int col = n0 + wn * 64 + n * 16 + lr;
              dst[col] = wgt * (acc[m][n][j] + bias[col]);
            }
          }
        }
      }
    }
  }
#undef STAGE
}

// ---------------- final: out += y_rank0 + y_rank1 ---------------------------
__global__ void final_add_kernel(float* __restrict__ out, const float* __restrict__ ybuf) {
  long i = ((long)blockIdx.x * 256 + threadIdx.x) * 4;
  float4 a = *(const float4*)(out + i);
  float4 b = *(const float4*)(ybuf + i);
  float4 c = *(const float4*)(ybuf + (long)T_TOK * D_DIM + i);
  a.x += b.x + c.x; a.y += b.y + c.y; a.z += b.z + c.z; a.w += b.w + c.w;
  *(float4*)(out + i) = a;
}

extern "C" void kernel_launch(void* const* d_in, const int* in_sizes, int n_in,
                              void* d_out, int out_size, void* d_ws, size_t ws_size,
                              hipStream_t stream) {
  (void)in_sizes; (void)n_in; (void)out_size; (void)ws_size;
  const float* x   = (const float*)d_in[0];
  const float* Wg  = (const float*)d_in[1];
  const float* W1  = (const float*)d_in[2];
  const float* b1  = (const float*)d_in[3];
  const float* W2  = (const float*)d_in[4];
  const float* b2  = (const float*)d_in[5];
  const float* Ws1 = (const float*)d_in[6];
  const float* bs1 = (const float*)d_in[7];
  const float* Ws2 = (const float*)d_in[8];
  const float* bs2 = (const float*)d_in[9];
  float* out = (float*)d_out;

  char* ws = (char*)d_ws;
  int*      cnt    = (int*)(ws + 0);
  int*      base   = (int*)(ws + 64);
  int*      tok    = (int*)(ws + 256);
  float*    wof    = (float*)(ws + 256 + 147456);
  int*      rankof = (int*)(ws + 256 + 2 * 147456);
  ushort_t* Xbf    = (ushort_t*)(ws + 442624);
  ushort_t* W1T    = (ushort_t*)(ws + 8831232);
  ushort_t* W2T    = (ushort_t*)(ws + 84328704);
  ushort_t* He     = (ushort_t*)(ws + 159826176);     // 12288 x 4096 bf16
  int*      nq     = (int*)(ws + 260489472);
  unsigned int* q1 = (unsigned int*)(ws + 260489536);          // <= 14 KB used
  unsigned int* q2 = (unsigned int*)(ws + 260489536 + 32768);  // <= 4 KB used
  float*    ybuf   = (float*)(ws + 261538048);

  hipMemsetAsync(cnt, 0, 64, stream);
  gate_kernel<<<T_TOK, 64, 0, stream>>>(x, Wg, cnt, tok, wof, rankof);
  scan_kernel<<<1, 64, 0, stream>>>(cnt, base);
  build_queue_kernel<<<9, 256, 0, stream>>>(cnt, q1, q2, nq);
  cvt_x_kernel<<<2048, 256, 0, stream>>>(x, Xbf);
  tcvt_kernel<<<dim3(64, 8, 9), 256, 0, stream>>>(W1, Ws1, W1T, 1024, 4096);
  tcvt_kernel<<<dim3(16, 32, 9), 256, 0, stream>>>(W2, Ws2, W2T, 4096, 1024);
  gemm_kernel<1024, 4096, 1><<<3328, 256, 0, stream>>>(
      Xbf, W1T, b1, bs1, cnt, base, tok, wof, rankof, q1, nq, He, ybuf, out);
  gemm_kernel<4096, 1024, 2><<<832, 256, 0, stream>>>(
      He, W2T, b2, bs2, cnt, base, tok, wof, rankof, q2, nq, He, ybuf, out);
  final_add_kernel<<<4096, 256, 0, stream>>>(out, ybuf);
}

// Round 9
// 524.269 us; speedup vs baseline: 1.1520x; 1.0450x over previous
//
#include <hip/hip_runtime.h>
#include <hip/hip_bf16.h>

typedef unsigned short ushort_t;
typedef __attribute__((ext_vector_type(4))) float f32x4;
typedef __attribute__((ext_vector_type(8))) short bf16x8;
typedef __attribute__((ext_vector_type(8))) unsigned short us8;

#define T_TOK 4096
#define D_DIM 1024
#define FF_DIM 4096
#define NE 8
#define ESTRIDE 4194304L  // 4096*1024 elements per expert weight matrix

__device__ __forceinline__ unsigned short f2bf(float f) {
  __hip_bfloat16 h = __float2bfloat16(f);
  return __builtin_bit_cast(unsigned short, h);
}
__device__ __forceinline__ float gelu_f(float v) {
  return 0.5f * v * (1.0f + erff(v * 0.70710678118654752440f));
}

// ---------------- gating: logits -> softmax top2 -> expert lists -------------
__global__ void gate_kernel(const float* __restrict__ x, const float* __restrict__ Wg,
                            int* __restrict__ cnt, int* __restrict__ tok,
                            float* __restrict__ wof, int* __restrict__ rankof) {
  const int t = blockIdx.x;
  const int lane = threadIdx.x;  // 64 threads = 1 wave
  const float* xr = x + (long)t * D_DIM;
  float acc[NE];
#pragma unroll
  for (int e = 0; e < NE; e++) acc[e] = 0.f;
#pragma unroll
  for (int i = 0; i < 16; i++) {
    int d = i * 64 + lane;
    float xv = xr[d];
    const float* wr = Wg + d * NE;
#pragma unroll
    for (int e = 0; e < NE; e++) acc[e] += xv * wr[e];
  }
#pragma unroll
  for (int off = 32; off > 0; off >>= 1) {
#pragma unroll
    for (int e = 0; e < NE; e++) acc[e] += __shfl_xor(acc[e], off, 64);
  }
  if (lane == 0) {
    int i0 = 0;
#pragma unroll
    for (int e = 1; e < NE; e++) if (acc[e] > acc[i0]) i0 = e;
    int i1 = -1;
#pragma unroll
    for (int e = 0; e < NE; e++) {
      if (e == i0) continue;
      if (i1 < 0 || acc[e] > acc[i1]) i1 = e;
    }
    float e1 = expf(acc[i1] - acc[i0]);
    float w0 = 1.f / (1.f + e1);
    float w1 = e1 * w0;
    int s0 = atomicAdd(&cnt[i0], 1);
    tok[i0 * T_TOK + s0] = t; wof[i0 * T_TOK + s0] = w0; rankof[i0 * T_TOK + s0] = 0;
    int s1 = atomicAdd(&cnt[i1], 1);
    tok[i1 * T_TOK + s1] = t; wof[i1 * T_TOK + s1] = w1; rankof[i1 * T_TOK + s1] = 1;
    tok[8 * T_TOK + t] = t; wof[8 * T_TOK + t] = 1.f; rankof[8 * T_TOK + t] = 0;
  }
}

__global__ void scan_kernel(int* cnt, int* base) {
  if (threadIdx.x == 0 && blockIdx.x == 0) {
    int s = 0;
    for (int e = 0; e < NE; e++) { base[e] = s; s += cnt[e]; }
    base[8] = s;      // always 8192
    cnt[8] = T_TOK;   // shared pseudo-expert gets all tokens
  }
}

// ---------------- build work-item queues (256-row m-tiles) ------------------
// GEMM1: N=16 n-tiles; supertile 2my x 4nx (A 2x0.5MB + B 4x0.5MB = 3MB <= L2).
// GEMM2: N=4 n-tiles; nx-major order (consecutive items share the 2MB B-panel).
__global__ void build_queue_kernel(const int* __restrict__ cnt,
                                   unsigned int* __restrict__ q1,
                                   unsigned int* __restrict__ q2,
                                   int* __restrict__ nq) {
  const int e = blockIdx.x;  // 9 blocks
  int off1 = 0, off2 = 0, tot1 = 0, tot2 = 0, M = 0;
  for (int i = 0; i < 9; i++) {
    int c = (i == 8) ? T_TOK : cnt[i];
    int m = (c + 255) >> 8;
    if (i < e) { off1 += m * 16; off2 += m * 4; }
    if (i == e) M = m;
    tot1 += m * 16; tot2 += m * 4;
  }
  for (int i = threadIdx.x; i < M * 16; i += 256) {
    int my = i >> 4, nx = i & 15;
    int ms = my >> 1, mi = my & 1, ns = nx >> 2, ni = nx & 3;
    int h = M - ms * 2; if (h > 2) h = 2;
    int pos = ms * 32 + ns * (h * 4) + mi * 4 + ni;
    q1[off1 + pos] = ((unsigned)e << 16) | ((unsigned)my << 8) | (unsigned)nx;
  }
  for (int i = threadIdx.x; i < M * 4; i += 256) {
    int my = i >> 2, nx = i & 3;
    int pos = nx * M + my;  // nx-major: share B panel
    q2[off2 + pos] = ((unsigned)e << 16) | ((unsigned)my << 8) | (unsigned)nx;
  }
  if (e == 0 && threadIdx.x == 0) { nq[0] = tot1; nq[1] = tot2; }
}

// ---------------- fp32 -> bf16 convert (x) ----------------------------------
__global__ void cvt_x_kernel(const float* __restrict__ src, ushort_t* __restrict__ dst) {
  long i = ((long)blockIdx.x * 256 + threadIdx.x) * 8;
  float4 v0 = *(const float4*)(src + i);
  float4 v1 = *(const float4*)(src + i + 4);
  us8 o;
  o[0] = f2bf(v0.x); o[1] = f2bf(v0.y); o[2] = f2bf(v0.z); o[3] = f2bf(v0.w);
  o[4] = f2bf(v1.x); o[5] = f2bf(v1.y); o[6] = f2bf(v1.z); o[7] = f2bf(v1.w);
  *(us8*)(dst + i) = o;
}

// ---------------- fp32 [R][C] -> bf16 [C][R] transpose-convert --------------
__global__ void tcvt_kernel(const float* __restrict__ W, const float* __restrict__ Wsh,
                            ushort_t* __restrict__ dst, int R, int C) {
  const float* src = (blockIdx.z == 8) ? Wsh : (W + (long)blockIdx.z * R * C);
  ushort_t* d = dst + (long)blockIdx.z * R * C;
  const int r0 = blockIdx.y * 128, c0 = blockIdx.x * 64;
  __shared__ ushort_t tile[64][136];
  const int t = threadIdx.x;
#pragma unroll
  for (int i = 0; i < 8; i++) {
    int lin = t + i * 256;
    int r = lin >> 4;
    int c = (lin & 15) * 4;
    float4 v = *(const float4*)(src + (long)(r0 + r) * C + c0 + c);
    tile[c + 0][r] = f2bf(v.x);
    tile[c + 1][r] = f2bf(v.y);
    tile[c + 2][r] = f2bf(v.z);
    tile[c + 3][r] = f2bf(v.w);
  }
  __syncthreads();
#pragma unroll
  for (int i = 0; i < 4; i++) {
    int lin = t + i * 256;
    int cc = lin >> 4, rp = lin & 15;
    us8 v = *(const us8*)&tile[cc][rp * 8];
    *(us8*)(d + (long)(c0 + cc) * R + r0 + rp * 8) = v;
  }
}

// ---------------- GEMM: 256x256 tile, 16 waves (4x4), BK=32 -----------------
// Arithmetic intensity 134 FLOP/B (2x the 128^2 tiles) -> breaks the measured
// ~8 TB/s cache-delivery roofline that pinned r1-r8 at ~494 TF.
// 1024-thread block, wave-tile 64x64 (acc[4][4]), counted-vmcnt double buffer
// (r8-proven): STAGE(t+1) 2 loads -> vmcnt(2) -> barrier -> 16 MFMA -> barrier.
// 64 KiB LDS, ~110 VGPR -> 16 waves/CU. Swizzle for 64B rows (2-way = free):
// stored 16B-slot = (chunk + (row>>1))&3, inverse on global source, LDS linear.
template <int K, int N, int PHASE>
__global__ __launch_bounds__(1024, 1) void gemm_kernel(
    const ushort_t* __restrict__ Abase, const ushort_t* __restrict__ WT,
    const float* __restrict__ bias_e, const float* __restrict__ bias_s,
    const int* __restrict__ cnt, const int* __restrict__ base,
    const int* __restrict__ tok, const float* __restrict__ wof,
    const int* __restrict__ rankof,
    const unsigned int* __restrict__ q, const int* __restrict__ nq_all,
    ushort_t* __restrict__ He, float* __restrict__ ybuf, float* __restrict__ out) {
  const int nq = nq_all[PHASE - 1];
  const int tid = threadIdx.x;
  const int w = tid >> 6, lane = tid & 63;
  const int wm = w >> 2, wn = w & 3;      // 4x4 wave grid; wave tile 64x64
  const int lr = lane & 15, lg = lane >> 4;

  __shared__ ushort_t lds_u[2 * 16384];  // 2 bufs x (A 16KB + B 16KB) = 64 KiB
  char* const lds = (char*)lds_u;

  // staging: thread covers LDS 16B-chunk tid: row = tid>>2, stored slot tid&3
  // holds global chunk cg = ((tid&3) - (row>>1)) & 3   [inverse swizzle]
  const int srow = tid >> 2;  // 0..255
  const int cg = ((tid & 3) - (srow >> 1)) & 3;

  // read offsets: row r, global chunk lg -> slot (lg + (r>>1)) & 3
  int offA[4], offB[4];
#pragma unroll
  for (int m = 0; m < 4; m++) {
    int r = wm * 64 + m * 16 + lr;
    offA[m] = r * 64 + (((lg + (r >> 1)) & 3) << 4);
  }
#pragma unroll
  for (int n = 0; n < 4; n++) {
    int r = wn * 64 + n * 16 + lr;
    offB[n] = r * 64 + (((lg + (r >> 1)) & 3) << 4);
  }

  constexpr int NT = K / 32;
  const int chunk = gridDim.x >> 3;
  const int vbid = (blockIdx.x & 7) * chunk + (blockIdx.x >> 3);

#define STAGE(buf_, kk_)                                                        \
  do {                                                                          \
    char* dd_ = lds + (buf_) * 32768 + tid * 16;                                \
    __builtin_amdgcn_global_load_lds(                                           \
        (const __attribute__((address_space(1))) void*)(pA + (kk_)),            \
        (__attribute__((address_space(3))) void*)(dd_), 16, 0, 0);              \
    __builtin_amdgcn_global_load_lds(                                           \
        (const __attribute__((address_space(1))) void*)(pB + (kk_)),            \
        (__attribute__((address_space(3))) void*)(dd_ + 16384), 16, 0, 0);      \
  } while (0)

  for (int it = vbid; it < nq; it += gridDim.x) {
    const unsigned int item = q[it];
    const int e = item >> 16;
    const int m0 = ((item >> 8) & 0xff) * 256;
    const int n0 = (item & 0xff) * 256;
    const int count = cnt[e];

    int rr = m0 + srow;
    int rc = (rr < count) ? rr : 0;  // clamp OOB rows
    long arow;
    if (PHASE == 1) arow = tok[e * T_TOK + rc];
    else            arow = (long)base[e] + rc;
    const ushort_t* pA = Abase + arow * (long)K + cg * 8;
    const ushort_t* pB = WT + (long)e * ESTRIDE + (long)(n0 + srow) * K + cg * 8;

    f32x4 acc[4][4] = {};

    __builtin_amdgcn_s_barrier();            // prev item's last reads done
    asm volatile("" ::: "memory");
    STAGE(0, 0);

    for (int t = 0; t < NT; t++) {
      if (t + 1 < NT) {
        STAGE((t + 1) & 1, (t + 1) * 32);
        asm volatile("s_waitcnt vmcnt(2)" ::: "memory");  // tile t resident
      } else {
        asm volatile("s_waitcnt vmcnt(0)" ::: "memory");
      }
      __builtin_amdgcn_s_barrier();          // all waves confirm tile t
      asm volatile("" ::: "memory");

      const char* aB = lds + (t & 1) * 32768;
      const char* bB = aB + 16384;
      bf16x8 av[4], bv[4];
#pragma unroll
      for (int m = 0; m < 4; m++) av[m] = *(const bf16x8*)(aB + offA[m]);
#pragma unroll
      for (int n = 0; n < 4; n++) bv[n] = *(const bf16x8*)(bB + offB[n]);
#pragma unroll
      for (int m = 0; m < 4; m++)
#pragma unroll
        for (int n = 0; n < 4; n++)
          acc[m][n] = __builtin_amdgcn_mfma_f32_16x16x32_bf16(av[m], bv[n], acc[m][n], 0, 0, 0);

      __builtin_amdgcn_s_barrier();          // reads(t) done before overwrite
      asm volatile("" ::: "memory");
    }

    const float* bias = (e == NE) ? bias_s : (bias_e + (long)e * N);
#pragma unroll
    for (int m = 0; m < 4; m++) {
#pragma unroll
      for (int j = 0; j < 4; j++) {
        int rloc = wm * 64 + m * 16 + lg * 4 + j;  // D row = (lane>>4)*4 + reg
        int rrr = m0 + rloc;
        if (rrr >= count) continue;
        if (PHASE == 1) {
          long orow = (long)base[e] + rrr;
#pragma unroll
          for (int n = 0; n < 4; n++) {
            int col = n0 + wn * 64 + n * 16 + lr;  // D col = lane&15
            float v = acc[m][n][j] + bias[col];
            He[orow * FF_DIM + col] = f2bf(gelu_f(v));
          }
        } else {
          int tt = tok[e * T_TOK + rrr];
          if (e == NE) {  // shared FFN -> d_out directly
#pragma unroll
            for (int n = 0; n < 4; n++) {
              int col = n0 + wn * 64 + n * 16 + lr;
              out[(long)tt * D_DIM + col] = acc[m][n][j] + bias[col];
            }
          } else {
            float wgt = wof[e * T_TOK + rrr];
            int rk = rankof[e * T_TOK + rrr];
            float* dst = ybuf + (long)rk * ((long)T_TOK * D_DIM) + (long)tt * D_DIM;
#pragma unroll
            for (int n = 0; n < 4; n++) {
              int col = n0 + wn * 64 + n * 16 + lr;
              dst[col] = wgt * (acc[m][n][j] + bias[col]);
            }
          }
        }
      }
    }
  }
#undef STAGE
}

// ---------------- final: out += y_rank0 + y_rank1 ---------------------------
__global__ void final_add_kernel(float* __restrict__ out, const float* __restrict__ ybuf) {
  long i = ((long)blockIdx.x * 256 + threadIdx.x) * 4;
  float4 a = *(const float4*)(out + i);
  float4 b = *(const float4*)(ybuf + i);
  float4 c = *(const float4*)(ybuf + (long)T_TOK * D_DIM + i);
  a.x += b.x + c.x; a.y += b.y + c.y; a.z += b.z + c.z; a.w += b.w + c.w;
  *(float4*)(out + i) = a;
}

extern "C" void kernel_launch(void* const* d_in, const int* in_sizes, int n_in,
                              void* d_out, int out_size, void* d_ws, size_t ws_size,
                              hipStream_t stream) {
  (void)in_sizes; (void)n_in; (void)out_size; (void)ws_size;
  const float* x   = (const float*)d_in[0];
  const float* Wg  = (const float*)d_in[1];
  const float* W1  = (const float*)d_in[2];
  const float* b1  = (const float*)d_in[3];
  const float* W2  = (const float*)d_in[4];
  const float* b2  = (const float*)d_in[5];
  const float* Ws1 = (const float*)d_in[6];
  const float* bs1 = (const float*)d_in[7];
  const float* Ws2 = (const float*)d_in[8];
  const float* bs2 = (const float*)d_in[9];
  float* out = (float*)d_out;

  char* ws = (char*)d_ws;
  int*      cnt    = (int*)(ws + 0);
  int*      base   = (int*)(ws + 64);
  int*      tok    = (int*)(ws + 256);
  float*    wof    = (float*)(ws + 256 + 147456);
  int*      rankof = (int*)(ws + 256 + 2 * 147456);
  ushort_t* Xbf    = (ushort_t*)(ws + 442624);
  ushort_t* W1T    = (ushort_t*)(ws + 8831232);
  ushort_t* W2T    = (ushort_t*)(ws + 84328704);
  ushort_t* He     = (ushort_t*)(ws + 159826176);     // 12544 x 4096 bf16 max
  int*      nq     = (int*)(ws + 260489472);
  unsigned int* q1 = (unsigned int*)(ws + 260489536);
  unsigned int* q2 = (unsigned int*)(ws + 260489536 + 32768);
  float*    ybuf   = (float*)(ws + 261538048);

  hipMemsetAsync(cnt, 0, 64, stream);
  gate_kernel<<<T_TOK, 64, 0, stream>>>(x, Wg, cnt, tok, wof, rankof);
  scan_kernel<<<1, 64, 0, stream>>>(cnt, base);
  build_queue_kernel<<<9, 256, 0, stream>>>(cnt, q1, q2, nq);
  cvt_x_kernel<<<2048, 256, 0, stream>>>(x, Xbf);
  tcvt_kernel<<<dim3(64, 8, 9), 256, 0, stream>>>(W1, Ws1, W1T, 1024, 4096);
  tcvt_kernel<<<dim3(16, 32, 9), 256, 0, stream>>>(W2, Ws2, W2T, 4096, 1024);
  gemm_kernel<1024, 4096, 1><<<512, 1024, 0, stream>>>(
      Xbf, W1T, b1, bs1, cnt, base, tok, wof, rankof, q1, nq, He, ybuf, out);
  gemm_kernel<4096, 1024, 2><<<256, 1024, 0, stream>>>(
      He, W2T, b2, bs2, cnt, base, tok, wof, rankof, q2, nq, He, ybuf, out);
  final_add_kernel<<<4096, 256, 0, stream>>>(out, ybuf);
}